// Round 4
// baseline (175.301 us; speedup 1.0000x reference)
//
#include <hip/hip_runtime.h>

#define D_K 576
#define NSLAB 18         // 576 / 32
#define LBDA_INV 2.0f    // 1/lbda, lbda=0.5
#define HALF_LBDA 0.5f
#define EPS 0.01f
#define DSTRIDE 136      // 128 + 8 bf16 pad (DP scratch)

#define NQROW 16384
#define NSROW 512
#define NQT 128          // query tiles of 128 rows
#define NST 4            // support tiles
#define NT 132
#define TILE_ELEMS (128 * D_K)    // ushorts per tile
#define SLAB_ELEMS (128 * 32)     // ushorts per slab (4096)
#define NJOBS (NT * NSLAB)        // 2376 (tile,slab) conversion jobs
#define NBLK 512

typedef __attribute__((ext_vector_type(8))) short short8;
typedef __attribute__((ext_vector_type(4))) short short4v;
typedef __attribute__((ext_vector_type(4))) float f32x4;

__device__ inline short f2bf(float f) {
    unsigned u = __float_as_uint(f);
    u += 0x7FFF + ((u >> 16) & 1);   // round-to-nearest-even
    return (short)(u >> 16);
}
__device__ inline float bf2f(unsigned short s) {
    return __uint_as_float(((unsigned)s) << 16);
}

// ---------------- soft-min helpers (lbda = 0.5) ----------------
__device__ inline float softmin3(float a, float b, float c) {
    float mn = fminf(a, fminf(b, c));
    float s = __expf(-LBDA_INV * (a - mn)) + __expf(-LBDA_INV * (b - mn)) +
              __expf(-LBDA_INV * (c - mn));
    return mn - HALF_LBDA * __logf(s);
}
__device__ inline float softmin2(float a, float b) {
    float mn = fminf(a, b);
    float s = __expf(-LBDA_INV * (a - mn)) + __expf(-LBDA_INV * (b - mn));
    return mn - HALF_LBDA * __logf(s);
}

// OTAM DP over an 8x8 dist tile; element (l,s) at d[l*RS + s*CS].
template <int RS, int CS>
__device__ float otam_dp(const float* d) {
    float prev[10], cur[10];
    prev[0] = 0.f;
#pragma unroll
    for (int m = 1; m <= 8; ++m) prev[m] = prev[m - 1] + d[0 * RS + (m - 1) * CS];
    prev[9] = prev[8];  // pad col, d=0
#pragma unroll
    for (int l = 1; l < 8; ++l) {
        cur[0] = 0.f;
        cur[1] = d[l * RS + 0 * CS] + softmin3(prev[0], 0.f, prev[1]);
#pragma unroll
        for (int m = 2; m <= 8; ++m)
            cur[m] = d[l * RS + (m - 1) * CS] + softmin2(prev[m - 1], cur[m - 1]);
        cur[9] = softmin3(prev[8], cur[8], prev[9]);
#pragma unroll
        for (int m = 0; m < 10; ++m) prev[m] = cur[m];
    }
    return prev[9];
}

// =====================================================================================
// Single persistent kernel:
//   phase 1: f32 -> bf16 chunk-major tile image (tb) + per-slab norm partials (psum)
//   global barrier (device-scope fences; 512 blocks co-resident: need 2/CU, cap >=3/CU)
//   phase 2: barrier-free MFMA K-loop (direct coalesced fragment loads) + epilogue + DP
// Tiled image: tile T, slab s, chunk p = c*128 + r (c = k-octet, r = row), 16B/chunk.
// =====================================================================================
__global__ __launch_bounds__(256, 2) void mega_kernel(
        const float* __restrict__ sup, const float* __restrict__ qry,
        unsigned short* __restrict__ tb, float* __restrict__ psum,
        unsigned* __restrict__ cnt, float* __restrict__ out) {
    __shared__ unsigned short Ds[128 * DSTRIDE];  // 34 KB; phase1 aliases first 16 KB
    __shared__ float qn_l[128], sn_l[128];

    const int t = threadIdx.x;
    const int b = blockIdx.x;

    // ---------------- phase 1: conversion jobs ----------------
    int parity = 0;
    for (int j = b; j < NJOBS; j += NBLK, parity ^= 1) {
        unsigned short* Ls = Ds + parity * SLAB_ELEMS;  // 8 KB double-buffer
        int tile = j / NSLAB;
        int slab = j - tile * NSLAB;
        const bool isq = tile < NQT;
        const float* src = (isq ? qry + (size_t)tile * 128 * D_K
                                : sup + (size_t)(tile - NQT) * 128 * D_K) + slab * 32;
        float* ps = psum + ((size_t)tile * NSLAB + slab) * 128;
#pragma unroll
        for (int i = 0; i < 4; ++i) {
            int idx = i * 256 + t;          // 0..1023 float4-chunks of the 128x32 slab
            int r = idx >> 3, c = idx & 7;
            float4 v = *(const float4*)(src + (size_t)r * D_K + c * 4);
            float ss = v.x * v.x + v.y * v.y + v.z * v.z + v.w * v.w;
            ss += __shfl_down(ss, 4);
            ss += __shfl_down(ss, 2);
            ss += __shfl_down(ss, 1);
            if ((t & 7) == 0) ps[r] = ss;   // partial sum-of-squares, this 32-col slab
            int c_in = c >> 1, half = c & 1;
            short4v o = {f2bf(v.x), f2bf(v.y), f2bf(v.z), f2bf(v.w)};
            *(short4v*)(&Ls[(c_in * 128 + r) * 8 + half * 4]) = o;
        }
        __syncthreads();   // single barrier per job; parity buffer prevents WAR race
        unsigned short* dst = tb + (size_t)tile * TILE_ELEMS + (size_t)slab * SLAB_ELEMS;
        *(short8*)(dst + t * 16) = *(const short8*)(&Ls[t * 16]);
        *(short8*)(dst + t * 16 + 8) = *(const short8*)(&Ls[t * 16 + 8]);
    }

    // ---------------- global barrier ----------------
    __syncthreads();                       // block's stores drained (vmcnt 0)
    if (t == 0) {
        __threadfence();                   // release: writeback this XCD's L2 to LLC
        atomicAdd(cnt, 1u);
        while (atomicAdd(cnt, 0u) < NBLK) __builtin_amdgcn_s_sleep(2);
        __threadfence();                   // acquire: invalidate stale L1/L2
    }
    __syncthreads();

    // ---------------- phase 2: GEMM + DP ----------------
    // XCD swizzle (perf heuristic only): 4 sblk-siblings of a qblk share an XCD
    const int xcd = b & 7, s2 = b >> 3;
    const int sblk = s2 >> 4;                 // 0..3
    const int qblk = xcd * 16 + (s2 & 15);    // 0..127

    // norms from per-slab partials (deterministic, no atomics)
    {
        const float* pq = psum + (size_t)qblk * NSLAB * 128;
        const float* ps = psum + (size_t)(NQT + sblk) * NSLAB * 128;
        if (t < 128) {
            float a = 0.f;
#pragma unroll
            for (int sl = 0; sl < NSLAB; ++sl) a += pq[sl * 128 + t];
            qn_l[t] = sqrtf(a);
        } else {
            int r = t - 128;
            float a = 0.f;
#pragma unroll
            for (int sl = 0; sl < NSLAB; ++sl) a += ps[sl * 128 + r];
            sn_l[r] = sqrtf(a);
        }
    }

    const unsigned short* At = tb + (size_t)qblk * TILE_ELEMS;
    const unsigned short* Bt = tb + (size_t)(NQT + sblk) * TILE_ELEMS;

    const int lane = t & 63;
    const int wave = t >> 6;
    const int wm = wave >> 1, wn = wave & 1;
    const int col16 = lane & 15, quad = lane >> 4;

    f32x4 acc[4][4];
#pragma unroll
    for (int i = 0; i < 4; ++i)
#pragma unroll
        for (int j = 0; j < 4; ++j) acc[i][j] = (f32x4){0.f, 0.f, 0.f, 0.f};

    // per-lane fragment offsets within a slab (ushorts); a quad's 16 lanes are contiguous
    int aoff[4], boff[4];
#pragma unroll
    for (int mt = 0; mt < 4; ++mt)
        aoff[mt] = (quad * 128 + wm * 64 + mt * 16 + col16) * 8;
#pragma unroll
    for (int nt = 0; nt < 4; ++nt)
        boff[nt] = (quad * 128 + wn * 64 + nt * 16 + col16) * 8;

#pragma unroll 3
    for (int sl = 0; sl < NSLAB; ++sl) {
        const unsigned short* Asl = At + sl * SLAB_ELEMS;
        const unsigned short* Bsl = Bt + sl * SLAB_ELEMS;
        short8 af[4], bf[4];
#pragma unroll
        for (int mt = 0; mt < 4; ++mt) af[mt] = *(const short8*)(Asl + aoff[mt]);
#pragma unroll
        for (int nt = 0; nt < 4; ++nt) bf[nt] = *(const short8*)(Bsl + boff[nt]);
#pragma unroll
        for (int mt = 0; mt < 4; ++mt)
#pragma unroll
            for (int nt = 0; nt < 4; ++nt)
                acc[mt][nt] = __builtin_amdgcn_mfma_f32_16x16x32_bf16(
                    af[mt], bf[nt], acc[mt][nt], 0, 0, 0);
    }
    __syncthreads();   // qn_l/sn_l visible; all waves past K-loop before Ds writes

    // epilogue: dist = 1 - num/(|q||s|+eps) -> Ds (bf16)
    // C/D layout: col = lane&15, row = quad*4 + reg
#pragma unroll
    for (int mt = 0; mt < 4; ++mt) {
#pragma unroll
        for (int reg = 0; reg < 4; ++reg) {
            int m = wm * 64 + mt * 16 + quad * 4 + reg;
            float qv = qn_l[m];
#pragma unroll
            for (int nt = 0; nt < 4; ++nt) {
                int n = wn * 64 + nt * 16 + col16;
                float sv = sn_l[n];
                float dist = 1.f - acc[mt][nt][reg] / (qv * sv + EPS);
                Ds[m * DSTRIDE + n] = (unsigned short)f2bf(dist);
            }
        }
    }
    __syncthreads();

    // DP phase: thread t owns pair (ql, sl)
    const int ql = t >> 4, sl = t & 15;
    float d[64];
#pragma unroll
    for (int l = 0; l < 8; ++l) {
        short8 rowv = *(const short8*)(&Ds[(ql * 8 + l) * DSTRIDE + sl * 8]);
#pragma unroll
        for (int j = 0; j < 8; ++j) d[l * 8 + j] = bf2f((unsigned short)rowv[j]);
    }
    float r1 = otam_dp<8, 1>(d);   // dists
    float r2 = otam_dp<1, 8>(d);   // dists^T
    int qg = qblk * 16 + ql, sg = sblk * 16 + sl;
    out[qg * 64 + sg] = -(r1 + r2);
}

extern "C" void kernel_launch(void* const* d_in, const int* in_sizes, int n_in,
                              void* d_out, int out_size, void* d_ws, size_t ws_size,
                              hipStream_t stream) {
    const float* sup = (const float*)d_in[0];   // [64, 8, 576]
    const float* qry = (const float*)d_in[1];   // [2048, 8, 576]
    float* out = (float*)d_out;                 // [2048, 64]

    // ws: tb bf16[132*128*576] (19.5 MB) | psum f32[132*18*128] (1.2 MB) | cnt u32
    unsigned short* tb = (unsigned short*)d_ws;
    float* psum = (float*)(tb + (size_t)NT * TILE_ELEMS);
    unsigned* cnt = (unsigned*)(psum + (size_t)NT * NSLAB * 128);

    hipMemsetAsync(cnt, 0, sizeof(unsigned), stream);   // barrier counter = 0 (ws is poisoned)
    mega_kernel<<<dim3(NBLK), dim3(256), 0, stream>>>(sup, qry, tb, psum, cnt, out);
}

// Round 5
// 120.264 us; speedup vs baseline: 1.4576x; 1.4576x over previous
//
#include <hip/hip_runtime.h>

#define D_K 576
#define NSLAB 18         // 576 / 32
#define LBDA_INV 2.0f    // 1/lbda, lbda=0.5
#define HALF_LBDA 0.5f
#define EPS 0.01f
#define DST 72           // Ds stride: 64 + 8 bf16 pad

#define NQT 128          // query tiles of 128 rows
#define NST 4            // support tiles of 128 rows
#define NT 132
#define TILE_ELEMS (128 * D_K)    // ushorts per tile
#define SLAB_ELEMS (128 * 32)     // ushorts per slab (4096)

typedef __attribute__((ext_vector_type(8))) short short8;
typedef __attribute__((ext_vector_type(4))) short short4v;
typedef __attribute__((ext_vector_type(4))) float f32x4;

__device__ inline short f2bf(float f) {
    unsigned u = __float_as_uint(f);
    u += 0x7FFF + ((u >> 16) & 1);   // round-to-nearest-even
    return (short)(u >> 16);
}
__device__ inline float bf2f(unsigned short s) {
    return __uint_as_float(((unsigned)s) << 16);
}

// ---------------- prep: f32 -> bf16 chunk-major tiles + per-slab norm partials ----------
// Tiled image: tile T, slab s, chunk p = c*128 + r (c = k-octet, r = row), 16B/chunk.
__global__ __launch_bounds__(256) void prep_kernel(
        const float* __restrict__ sup, const float* __restrict__ qry,
        unsigned short* __restrict__ tb, float* __restrict__ psum) {
    __shared__ unsigned short Ls[SLAB_ELEMS];   // 8 KB, chunk-major
    const int t = threadIdx.x;
    const int slab = blockIdx.x;    // 0..17
    const int tile = blockIdx.y;    // 0..131
    const bool isq = tile < NQT;
    const float* src = (isq ? qry + (size_t)tile * 128 * D_K
                            : sup + (size_t)(tile - NQT) * 128 * D_K) + slab * 32;
    float* ps = psum + ((size_t)tile * NSLAB + slab) * 128;

#pragma unroll
    for (int i = 0; i < 4; ++i) {
        int idx = i * 256 + t;          // 0..1023 float4-chunks of the 128x32 slab
        int r = idx >> 3, c = idx & 7;
        float4 v = *(const float4*)(src + (size_t)r * D_K + c * 4);
        float ss = v.x * v.x + v.y * v.y + v.z * v.z + v.w * v.w;
        ss += __shfl_down(ss, 4);
        ss += __shfl_down(ss, 2);
        ss += __shfl_down(ss, 1);
        if ((t & 7) == 0) ps[r] = ss;   // partial sum-of-squares for this 32-col slab
        int c_in = c >> 1, half = c & 1;
        short4v o = {f2bf(v.x), f2bf(v.y), f2bf(v.z), f2bf(v.w)};
        *(short4v*)(&Ls[(c_in * 128 + r) * 8 + half * 4]) = o;
    }
    __syncthreads();
    unsigned short* dst = tb + (size_t)tile * TILE_ELEMS + (size_t)slab * SLAB_ELEMS;
    *(short8*)(dst + t * 16) = *(const short8*)(&Ls[t * 16]);
    *(short8*)(dst + t * 16 + 8) = *(const short8*)(&Ls[t * 16 + 8]);
}

// ---------------- soft-min helpers (lbda = 0.5) ----------------
__device__ inline float softmin3(float a, float b, float c) {
    float mn = fminf(a, fminf(b, c));
    float s = __expf(-LBDA_INV * (a - mn)) + __expf(-LBDA_INV * (b - mn)) +
              __expf(-LBDA_INV * (c - mn));
    return mn - HALF_LBDA * __logf(s);
}
__device__ inline float softmin2(float a, float b) {
    float mn = fminf(a, b);
    float s = __expf(-LBDA_INV * (a - mn)) + __expf(-LBDA_INV * (b - mn));
    return mn - HALF_LBDA * __logf(s);
}

// OTAM DP over an 8x8 dist tile; element (l,s) at d[l*RS + s*CS].
template <int RS, int CS>
__device__ float otam_dp(const float* d) {
    float prev[10], cur[10];
    prev[0] = 0.f;
#pragma unroll
    for (int m = 1; m <= 8; ++m) prev[m] = prev[m - 1] + d[0 * RS + (m - 1) * CS];
    prev[9] = prev[8];  // pad col, d=0
#pragma unroll
    for (int l = 1; l < 8; ++l) {
        cur[0] = 0.f;
        cur[1] = d[l * RS + 0 * CS] + softmin3(prev[0], 0.f, prev[1]);
#pragma unroll
        for (int m = 2; m <= 8; ++m)
            cur[m] = d[l * RS + (m - 1) * CS] + softmin2(prev[m - 1], cur[m - 1]);
        cur[9] = softmin3(prev[8], cur[8], prev[9]);
#pragma unroll
        for (int m = 0; m < 10; ++m) prev[m] = cur[m];
    }
    return prev[9];
}

// ---------------- fused: 128q x 64s tile, 1024 blocks (4/CU), barrier-free K-loop -------
__global__ __launch_bounds__(256, 4) void fused_kernel(
        const unsigned short* __restrict__ tb, const float* __restrict__ psum,
        float* __restrict__ out) {
    __shared__ unsigned short Ds[128 * DST];   // 18.4 KB
    __shared__ float qn_l[128], sn_l[64];

    const int t = threadIdx.x;
    // XCD swizzle: the 8 s-halves sharing a qblk land on one XCD (A reuse in its L2)
    const int b = blockIdx.x;
    const int xcd = b & 7, s2 = b >> 3;
    const int shalf = s2 >> 4;                // 0..7 (64-row half of a B tile)
    const int qblk = xcd * 16 + (s2 & 15);    // 0..127
    const int sbt = shalf >> 1;               // B tile 0..3
    const int hbase = (shalf & 1) * 64;       // row base inside B tile

    // norms from per-slab partials (deterministic, no atomics)
    {
        if (t < 128) {
            const float* pq = psum + (size_t)qblk * NSLAB * 128;
            float a = 0.f;
#pragma unroll
            for (int sl = 0; sl < NSLAB; ++sl) a += pq[sl * 128 + t];
            qn_l[t] = sqrtf(a);
        } else if (t < 192) {
            int r = t - 128;
            const float* ps = psum + (size_t)(NQT + sbt) * NSLAB * 128;
            float a = 0.f;
#pragma unroll
            for (int sl = 0; sl < NSLAB; ++sl) a += ps[sl * 128 + hbase + r];
            sn_l[r] = sqrtf(a);
        }
    }

    const unsigned short* At = tb + (size_t)qblk * TILE_ELEMS;
    const unsigned short* Bt = tb + (size_t)(NQT + sbt) * TILE_ELEMS;

    const int lane = t & 63;
    const int wave = t >> 6;
    const int wm = wave >> 1, wn = wave & 1;   // wave: q-rows [wm*64,+64) x s-cols [wn*32,+32)
    const int col16 = lane & 15, quad = lane >> 4;

    f32x4 acc[4][2];
#pragma unroll
    for (int i = 0; i < 4; ++i)
#pragma unroll
        for (int j = 0; j < 2; ++j) acc[i][j] = (f32x4){0.f, 0.f, 0.f, 0.f};

    // per-lane fragment offsets within a slab (ushorts); a quad's 16 lanes are contiguous
    int aoff[4], boff[2];
#pragma unroll
    for (int mt = 0; mt < 4; ++mt)
        aoff[mt] = (quad * 128 + wm * 64 + mt * 16 + col16) * 8;
#pragma unroll
    for (int nt = 0; nt < 2; ++nt)
        boff[nt] = (quad * 128 + hbase + wn * 32 + nt * 16 + col16) * 8;

#pragma unroll 3
    for (int sl = 0; sl < NSLAB; ++sl) {
        const unsigned short* Asl = At + sl * SLAB_ELEMS;
        const unsigned short* Bsl = Bt + sl * SLAB_ELEMS;
        short8 af[4], bf[2];
#pragma unroll
        for (int mt = 0; mt < 4; ++mt) af[mt] = *(const short8*)(Asl + aoff[mt]);
#pragma unroll
        for (int nt = 0; nt < 2; ++nt) bf[nt] = *(const short8*)(Bsl + boff[nt]);
#pragma unroll
        for (int mt = 0; mt < 4; ++mt)
#pragma unroll
            for (int nt = 0; nt < 2; ++nt)
                acc[mt][nt] = __builtin_amdgcn_mfma_f32_16x16x32_bf16(
                    af[mt], bf[nt], acc[mt][nt], 0, 0, 0);
    }
    __syncthreads();   // qn_l/sn_l visible; all waves past K-loop before Ds writes

    // epilogue: dist = 1 - num/(|q||s|+eps) -> Ds (bf16)
    // C/D layout: col = lane&15, row = quad*4 + reg
#pragma unroll
    for (int mt = 0; mt < 4; ++mt) {
#pragma unroll
        for (int reg = 0; reg < 4; ++reg) {
            int m = wm * 64 + mt * 16 + quad * 4 + reg;
            float qv = qn_l[m];
#pragma unroll
            for (int nt = 0; nt < 2; ++nt) {
                int n = wn * 32 + nt * 16 + col16;
                float sv = sn_l[n];
                float dist = 1.f - acc[mt][nt][reg] / (qv * sv + EPS);
                Ds[m * DST + n] = (unsigned short)f2bf(dist);
            }
        }
    }
    __syncthreads();

    // DP phase: threads 0..127 own pair (ql 0..15, sl 0..7)
    if (t < 128) {
        const int ql = t >> 3, sl = t & 7;
        float d[64];
#pragma unroll
        for (int l = 0; l < 8; ++l) {
            short8 rowv = *(const short8*)(&Ds[(ql * 8 + l) * DST + sl * 8]);
#pragma unroll
            for (int j = 0; j < 8; ++j) d[l * 8 + j] = bf2f((unsigned short)rowv[j]);
        }
        float r1 = otam_dp<8, 1>(d);   // dists
        float r2 = otam_dp<1, 8>(d);   // dists^T
        int qg = qblk * 16 + ql, sg = shalf * 8 + sl;
        out[qg * 64 + sg] = -(r1 + r2);
    }
}

extern "C" void kernel_launch(void* const* d_in, const int* in_sizes, int n_in,
                              void* d_out, int out_size, void* d_ws, size_t ws_size,
                              hipStream_t stream) {
    const float* sup = (const float*)d_in[0];   // [64, 8, 576]
    const float* qry = (const float*)d_in[1];   // [2048, 8, 576]
    float* out = (float*)d_out;                 // [2048, 64]

    // ws: tb bf16[132*128*576] (19.5 MB) | psum f32[132*18*128] (1.2 MB)
    unsigned short* tb = (unsigned short*)d_ws;
    float* psum = (float*)(tb + (size_t)NT * TILE_ELEMS);

    prep_kernel<<<dim3(NSLAB, NT), dim3(256), 0, stream>>>(sup, qry, tb, psum);
    fused_kernel<<<dim3(1024), dim3(256), 0, stream>>>(tb, psum, out);
}

// Round 6
// 112.139 us; speedup vs baseline: 1.5632x; 1.0724x over previous
//
#include <hip/hip_runtime.h>

#define D_K 576
#define NSLAB 18         // 576 / 32
#define LBDA_INV 2.0f    // 1/lbda, lbda=0.5
#define HALF_LBDA 0.5f
#define EPS 0.01f
#define DSTRIDE 136      // Ds stride: 128 + 8 bf16 pad

#define NQT 128          // query tiles of 128 rows
#define NST 4            // support tiles of 128 rows
#define NT 132
#define TILE_ELEMS (128 * D_K)    // ushorts per tile (73728)
#define SLAB_ELEMS (128 * 32)     // ushorts per slab (4096 = 8 KB)

typedef __attribute__((ext_vector_type(8))) short short8;
typedef __attribute__((ext_vector_type(4))) short short4v;
typedef __attribute__((ext_vector_type(4))) float f32x4;

__device__ inline short f2bf(float f) {
    unsigned u = __float_as_uint(f);
    u += 0x7FFF + ((u >> 16) & 1);   // round-to-nearest-even
    return (short)(u >> 16);
}
__device__ inline float bf2f(unsigned short s) {
    return __uint_as_float(((unsigned)s) << 16);
}

// async 16B global->LDS; LDS dst is wave-uniform base, lane i lands at base + i*16
__device__ inline void load_lds16(const void* g, void* l) {
    __builtin_amdgcn_global_load_lds(
        (const __attribute__((address_space(1))) unsigned int*)g,
        (__attribute__((address_space(3))) unsigned int*)l,
        16, 0, 0);
}

// ---------------- prep: f32 -> bf16 chunk-major tiles + per-slab norm partials ----------
// Tiled image: tile T, slab s, chunk p = c*128 + r (c = k-octet, r = row), 16B/chunk,
// chunks stored contiguously by p -> a wave reading 64 consecutive chunks is one 1KB seg.
__global__ __launch_bounds__(256) void prep_kernel(
        const float* __restrict__ sup, const float* __restrict__ qry,
        unsigned short* __restrict__ tb, float* __restrict__ psum) {
    __shared__ unsigned short Ls[SLAB_ELEMS];   // 8 KB, chunk-major
    const int t = threadIdx.x;
    const int slab = blockIdx.x;    // 0..17
    const int tile = blockIdx.y;    // 0..131
    const bool isq = tile < NQT;
    const float* src = (isq ? qry + (size_t)tile * 128 * D_K
                            : sup + (size_t)(tile - NQT) * 128 * D_K) + slab * 32;
    float* ps = psum + ((size_t)tile * NSLAB + slab) * 128;

#pragma unroll
    for (int i = 0; i < 4; ++i) {
        int idx = i * 256 + t;          // 0..1023 float4-chunks of the 128x32 slab
        int r = idx >> 3, c = idx & 7;
        float4 v = *(const float4*)(src + (size_t)r * D_K + c * 4);
        float ss = v.x * v.x + v.y * v.y + v.z * v.z + v.w * v.w;
        ss += __shfl_down(ss, 4);
        ss += __shfl_down(ss, 2);
        ss += __shfl_down(ss, 1);
        if ((t & 7) == 0) ps[r] = ss;   // partial sum-of-squares for this 32-col slab
        int c_in = c >> 1, half = c & 1;
        short4v o = {f2bf(v.x), f2bf(v.y), f2bf(v.z), f2bf(v.w)};
        *(short4v*)(&Ls[(c_in * 128 + r) * 8 + half * 4]) = o;
    }
    __syncthreads();
    unsigned short* dst = tb + (size_t)tile * TILE_ELEMS + (size_t)slab * SLAB_ELEMS;
    *(short8*)(dst + t * 16) = *(const short8*)(&Ls[t * 16]);
    *(short8*)(dst + t * 16 + 8) = *(const short8*)(&Ls[t * 16 + 8]);
}

// ---------------- soft-min helpers (lbda = 0.5) ----------------
__device__ inline float softmin3(float a, float b, float c) {
    float mn = fminf(a, fminf(b, c));
    float s = __expf(-LBDA_INV * (a - mn)) + __expf(-LBDA_INV * (b - mn)) +
              __expf(-LBDA_INV * (c - mn));
    return mn - HALF_LBDA * __logf(s);
}
__device__ inline float softmin2(float a, float b) {
    float mn = fminf(a, b);
    float s = __expf(-LBDA_INV * (a - mn)) + __expf(-LBDA_INV * (b - mn));
    return mn - HALF_LBDA * __logf(s);
}

// OTAM DP over an 8x8 dist tile; element (l,s) at d[l*RS + s*CS].
template <int RS, int CS>
__device__ float otam_dp(const float* d) {
    float prev[10], cur[10];
    prev[0] = 0.f;
#pragma unroll
    for (int m = 1; m <= 8; ++m) prev[m] = prev[m - 1] + d[0 * RS + (m - 1) * CS];
    prev[9] = prev[8];  // pad col, d=0
#pragma unroll
    for (int l = 1; l < 8; ++l) {
        cur[0] = 0.f;
        cur[1] = d[l * RS + 0 * CS] + softmin3(prev[0], 0.f, prev[1]);
#pragma unroll
        for (int m = 2; m <= 8; ++m)
            cur[m] = d[l * RS + (m - 1) * CS] + softmin2(prev[m - 1], cur[m - 1]);
        cur[9] = softmin3(prev[8], cur[8], prev[9]);
#pragma unroll
        for (int m = 0; m < 10; ++m) prev[m] = cur[m];
    }
    return prev[9];
}

// ---------------- fused: 128x128 tile, LDS-staged K-loop (global_load_lds x16) + DP -----
// Each block reads its A and B tiles from global exactly ONCE (coalesced 1KB wave segs),
// MFMA fragments come from LDS via conflict-free ds_read_b128.
__global__ __launch_bounds__(256, 2) void fused_kernel(
        const unsigned short* __restrict__ tb, const float* __restrict__ psum,
        float* __restrict__ out) {
    // smem serves as As0|As1|Bs0|Bs1 (4 x 8 KB) in the K-loop, then as Ds (34.8 KB) in DP
    __shared__ unsigned short smem[128 * DSTRIDE];   // 17408 ushorts = 34816 B
    __shared__ float qn_l[128], sn_l[128];
    unsigned short* As0 = smem;
    unsigned short* As1 = smem + SLAB_ELEMS;
    unsigned short* Bs0 = smem + 2 * SLAB_ELEMS;
    unsigned short* Bs1 = smem + 3 * SLAB_ELEMS;
    unsigned short* Ds = smem;

    const int t = threadIdx.x;
    // XCD swizzle (perf heuristic): 4 sblk-siblings of a qblk share an XCD (A L2 reuse)
    const int b = blockIdx.x;
    const int xcd = b & 7, s2 = b >> 3;
    const int sblk = s2 >> 4;                 // 0..3
    const int qblk = xcd * 16 + (s2 & 15);    // 0..127

    // norms from per-slab partials (deterministic, no atomics)
    if (t < 128) {
        const float* pq = psum + (size_t)qblk * NSLAB * 128;
        float a = 0.f;
#pragma unroll
        for (int sl = 0; sl < NSLAB; ++sl) a += pq[sl * 128 + t];
        qn_l[t] = sqrtf(a);
    } else {
        int r = t - 128;
        const float* ps = psum + (size_t)(NQT + sblk) * NSLAB * 128;
        float a = 0.f;
#pragma unroll
        for (int sl = 0; sl < NSLAB; ++sl) a += ps[sl * 128 + r];
        sn_l[r] = sqrtf(a);
    }

    const unsigned short* At = tb + (size_t)qblk * TILE_ELEMS;
    const unsigned short* Bt = tb + (size_t)(NQT + sblk) * TILE_ELEMS;

    const int lane = t & 63;
    const int wave = t >> 6;
    const int wm = wave >> 1, wn = wave & 1;
    const int col16 = lane & 15, quad = lane >> 4;

    f32x4 acc[4][4];
#pragma unroll
    for (int i = 0; i < 4; ++i)
#pragma unroll
        for (int j = 0; j < 4; ++j) acc[i][j] = (f32x4){0.f, 0.f, 0.f, 0.f};

    // fragment offsets (ushorts) within one staged slab: chunk = quad*128 + row
    int aoff[4], boff[4];
#pragma unroll
    for (int mt = 0; mt < 4; ++mt)
        aoff[mt] = (quad * 128 + wm * 64 + mt * 16 + col16) * 8;
#pragma unroll
    for (int nt = 0; nt < 4; ++nt)
        boff[nt] = (quad * 128 + wn * 64 + nt * 16 + col16) * 8;

    // K-loop: BK=64 (2 slabs per iteration), 9 iterations, 2 barriers each
    for (int j2 = 0; j2 < 9; ++j2) {
        const unsigned short* A0 = At + (size_t)(2 * j2) * SLAB_ELEMS;
        const unsigned short* A1 = A0 + SLAB_ELEMS;
        const unsigned short* B0 = Bt + (size_t)(2 * j2) * SLAB_ELEMS;
        const unsigned short* B1 = B0 + SLAB_ELEMS;
        // stage: each wave moves 128 chunks of each slab (2 x 1KB instrs per slab)
#pragma unroll
        for (int i = 0; i < 2; ++i) {
            int cb = wave * 128 + i * 64;            // wave-uniform chunk base
            int go = (cb + lane) * 8;                // per-lane global ushort offset
            load_lds16(A0 + go, &As0[cb * 8]);
            load_lds16(A1 + go, &As1[cb * 8]);
            load_lds16(B0 + go, &Bs0[cb * 8]);
            load_lds16(B1 + go, &Bs1[cb * 8]);
        }
        __syncthreads();   // drain vmcnt: staged tiles visible

#pragma unroll
        for (int h = 0; h < 2; ++h) {
            const unsigned short* Ah = h ? As1 : As0;
            const unsigned short* Bh = h ? Bs1 : Bs0;
            short8 af[4], bf[4];
#pragma unroll
            for (int mt = 0; mt < 4; ++mt) af[mt] = *(const short8*)(Ah + aoff[mt]);
#pragma unroll
            for (int nt = 0; nt < 4; ++nt) bf[nt] = *(const short8*)(Bh + boff[nt]);
#pragma unroll
            for (int mt = 0; mt < 4; ++mt)
#pragma unroll
                for (int nt = 0; nt < 4; ++nt)
                    acc[mt][nt] = __builtin_amdgcn_mfma_f32_16x16x32_bf16(
                        af[mt], bf[nt], acc[mt][nt], 0, 0, 0);
        }
        __syncthreads();   // all reads done before next stage overwrites
    }

    // epilogue: dist = 1 - num/(|q||s|+eps) -> Ds (bf16); Ds aliases staging buffers
    // (safe: trailing barrier above). C/D layout: col = lane&15, row = quad*4 + reg
#pragma unroll
    for (int mt = 0; mt < 4; ++mt) {
#pragma unroll
        for (int reg = 0; reg < 4; ++reg) {
            int m = wm * 64 + mt * 16 + quad * 4 + reg;
            float qv = qn_l[m];
#pragma unroll
            for (int nt = 0; nt < 4; ++nt) {
                int n = wn * 64 + nt * 16 + col16;
                float sv = sn_l[n];
                float dist = 1.f - acc[mt][nt][reg] / (qv * sv + EPS);
                Ds[m * DSTRIDE + n] = (unsigned short)f2bf(dist);
            }
        }
    }
    __syncthreads();

    // DP phase: thread t owns pair (ql, sl)
    const int ql = t >> 4, sl = t & 15;
    float d[64];
#pragma unroll
    for (int l = 0; l < 8; ++l) {
        short8 rowv = *(const short8*)(&Ds[(ql * 8 + l) * DSTRIDE + sl * 8]);
#pragma unroll
        for (int j = 0; j < 8; ++j) d[l * 8 + j] = bf2f((unsigned short)rowv[j]);
    }
    float r1 = otam_dp<8, 1>(d);   // dists
    float r2 = otam_dp<1, 8>(d);   // dists^T
    int qg = qblk * 16 + ql, sg = sblk * 16 + sl;
    out[qg * 64 + sg] = -(r1 + r2);
}

extern "C" void kernel_launch(void* const* d_in, const int* in_sizes, int n_in,
                              void* d_out, int out_size, void* d_ws, size_t ws_size,
                              hipStream_t stream) {
    const float* sup = (const float*)d_in[0];   // [64, 8, 576]
    const float* qry = (const float*)d_in[1];   // [2048, 8, 576]
    float* out = (float*)d_out;                 // [2048, 64]

    // ws: tb bf16[132*128*576] (19.5 MB) | psum f32[132*18*128] (1.2 MB)
    unsigned short* tb = (unsigned short*)d_ws;
    float* psum = (float*)(tb + (size_t)NT * TILE_ELEMS);

    prep_kernel<<<dim3(NSLAB, NT), dim3(256), 0, stream>>>(sup, qry, tb, psum);
    fused_kernel<<<dim3(512), dim3(256), 0, stream>>>(tb, psum, out);
}